// Round 6
// baseline (463.491 us; speedup 1.0000x reference)
//
#include <hip/hip_runtime.h>
#include <hip/hip_bf16.h>
#include <math.h>

// ---------------------------------------------------------------------------
// VAR quantizer forward. Round 6: k_nn re-tiled for >=4-8 blocks/CU + setprio;
// k_scale 1024-thread with LDS-staged padded weights (no exposed L2 latency),
// one image row per wave. Conv/NN arithmetic bitwise-identical to round 5.
// Output: [f_hat 1048576][loss 1][idx-as-float 87040]
// ---------------------------------------------------------------------------

#define B_  128
#define V_  4096
#define SN_ 10
#define NPIX_ (B_*32*256)   // 1048576

// ws layout (float offsets)
#define WS_FREST   0
#define WS_PD      1048576
#define WS_PI      1572864
#define WS_ESQ     2097152
#define WS_TW      2101248
#define WS_TI      2101824
#define WS_LOSSP   2102400
#define WS_RESTH   2105344
#define WS_RESTM   2629632
#define WS_RESTL   3153920
#define WS_EMBH    3678208
#define WS_EMBM    3743744
#define WS_EMBL    3809280
#define WS_WSPL    3874816
// end 3930112 floats = 15.0 MB

typedef __attribute__((ext_vector_type(8))) short short8_t;
typedef __attribute__((ext_vector_type(4))) float f32x4;
#define MFMA(a,b,c) __builtin_amdgcn_mfma_f32_16x16x32_bf16((a),(b),(c),0,0,0)

__device__ inline void gl_lds16(const void* g, void* l) {
  __builtin_amdgcn_global_load_lds((const __attribute__((address_space(1))) void*)g,
                                   (__attribute__((address_space(3))) void*)l, 16, 0, 0);
}
__device__ inline void gl_lds4(const void* g, void* l) {
  __builtin_amdgcn_global_load_lds((const __attribute__((address_space(1))) void*)g,
                                   (__attribute__((address_space(3))) void*)l, 4, 0, 0);
}

// split f32 -> 3 truncated bf16 levels (captures ~24 bits)
__device__ inline void split3(float a, ushort* h, ushort* m, ushort* l) {
  unsigned ua = __float_as_uint(a);
  ushort uh = (ushort)(ua >> 16);
  float fh = __uint_as_float((unsigned)uh << 16);
  float r1 = a - fh;
  ushort um = (ushort)(__float_as_uint(r1) >> 16);
  float fm = __uint_as_float((unsigned)um << 16);
  float r2 = r1 - fm;
  ushort ul = (ushort)(__float_as_uint(r2) >> 16);
  *h = uh; *m = um; *l = ul;
}

// DPP lane shifts within 16-lane rows; bound_ctrl=1 -> zero fill (SAME pad)
__device__ inline short8_t s8_from_laneM1(short8_t v) {   // value from lane-1 (X-1)
  union { short8_t s; unsigned u[4]; } a, r;
  a.s = v;
#pragma unroll
  for (int i = 0; i < 4; ++i)
    r.u[i] = __builtin_amdgcn_update_dpp(0u, a.u[i], 0x111, 0xF, 0xF, true);
  return r.s;
}
__device__ inline short8_t s8_from_laneP1(short8_t v) {   // value from lane+1 (X+1)
  union { short8_t s; unsigned u[4]; } a, r;
  a.s = v;
#pragma unroll
  for (int i = 0; i < 4; ++i)
    r.u[i] = __builtin_amdgcn_update_dpp(0u, a.u[i], 0x101, 0xF, 0xF, true);
  return r.s;
}

// --------------------------- prep kernel (4 roles) --------------------------

__global__ __launch_bounds__(256) void k_prep(const float* __restrict__ emb,
                                              const float* __restrict__ f,
                                              const float* __restrict__ phiW,
                                              float* __restrict__ esq,
                                              ushort* __restrict__ eh,
                                              ushort* __restrict__ em,
                                              ushort* __restrict__ el,
                                              float* __restrict__ tw,
                                              int* __restrict__ ti,
                                              ushort* __restrict__ rh,
                                              ushort* __restrict__ rm,
                                              ushort* __restrict__ rl,
                                              ushort* __restrict__ wspl) {
  int bx = blockIdx.x, t = threadIdx.x;
  if (bx < 16) {
    int v = bx * 256 + t;
    const float4* e4 = (const float4*)(emb + (size_t)v * 32);
    float s = 0.f;
#pragma unroll
    for (int half = 0; half < 4; ++half) {
      float4 x0 = e4[half * 2], x1 = e4[half * 2 + 1];
      s += x0.x * x0.x + x0.y * x0.y + x0.z * x0.z + x0.w * x0.w;
      s += x1.x * x1.x + x1.y * x1.y + x1.z * x1.z + x1.w * x1.w;
      float xs[8] = {x0.x, x0.y, x0.z, x0.w, x1.x, x1.y, x1.z, x1.w};
      ushort hs[8], ms[8], ls[8];
#pragma unroll
      for (int j = 0; j < 8; ++j) split3(xs[j], &hs[j], &ms[j], &ls[j]);
      uint4 ph, pm, pl;
      ph.x = (unsigned)hs[0] | ((unsigned)hs[1] << 16); ph.y = (unsigned)hs[2] | ((unsigned)hs[3] << 16);
      ph.z = (unsigned)hs[4] | ((unsigned)hs[5] << 16); ph.w = (unsigned)hs[6] | ((unsigned)hs[7] << 16);
      pm.x = (unsigned)ms[0] | ((unsigned)ms[1] << 16); pm.y = (unsigned)ms[2] | ((unsigned)ms[3] << 16);
      pm.z = (unsigned)ms[4] | ((unsigned)ms[5] << 16); pm.w = (unsigned)ms[6] | ((unsigned)ms[7] << 16);
      pl.x = (unsigned)ls[0] | ((unsigned)ls[1] << 16); pl.y = (unsigned)ls[2] | ((unsigned)ls[3] << 16);
      pl.z = (unsigned)ls[4] | ((unsigned)ls[5] << 16); pl.w = (unsigned)ls[6] | ((unsigned)ls[7] << 16);
      ((uint4*)(eh + (size_t)v * 32))[half] = ph;
      ((uint4*)(em + (size_t)v * 32))[half] = pm;
      ((uint4*)(el + (size_t)v * 32))[half] = pl;
    }
    esq[v] = -0.5f * s;
  } else if (bx == 16) {
    if (t >= 144) return;
    const int pns[9] = {1, 2, 3, 4, 5, 6, 8, 10, 13};
    int si = t / 16, Y = t % 16;
    int pn = pns[si];
    double src = (Y + 0.5) * (double)pn / 16.0 - 0.5;
    double fl = floor(src);
    const double a = -0.75;
#pragma unroll
    for (int k = 0; k < 4; ++k) {
      double x = fabs(src - (fl + (k - 1)));
      double w;
      if (x <= 1.0)      w = (a + 2.0) * x * x * x - (a + 3.0) * x * x + 1.0;
      else if (x < 2.0)  w = a * x * x * x - 5.0 * a * x * x + 8.0 * a * x - 4.0 * a;
      else               w = 0.0;
      int id = (int)fl + (k - 1);
      id = id < 0 ? 0 : (id > pn - 1 ? pn - 1 : id);
      tw[si * 64 + Y * 4 + k] = (float)w;
      ti[si * 64 + Y * 4 + k] = id;
    }
  } else if (bx < 33) {
    // phi weight split: wspl[phi][lvl][q][o][ci] bf16x3
    int i = (bx - 17) * 256 + t;   // 4096 (phi,o,ci)
    int phi = i >> 10, o = (i >> 5) & 31, ci = i & 31;
    const float* src = phiW + (((size_t)phi * 32 + o) * 32 + ci) * 9;
    ushort* dst = wspl + (size_t)phi * 27648;
#pragma unroll
    for (int q = 0; q < 9; ++q) {
      ushort uh, um, ul;
      split3(src[q], &uh, &um, &ul);
      dst[(size_t)(0 * 9 + q) * 1024 + o * 32 + ci] = uh;
      dst[(size_t)(9 + q) * 1024 + o * 32 + ci] = um;
      dst[(size_t)(18 + q) * 1024 + o * 32 + ci] = ul;
    }
  } else {
    // si=0 NN input: area-pool f to 1x1 -> [n][c] 3-level bf16
    int tid = (bx - 33) * 256 + t;   // 4096
    int c = tid & 31, n = tid >> 5;
    const float* base = f + ((size_t)n * 32 + c) * 256;
    float s = 0.f;
    for (int yy = 0; yy < 16; ++yy)
      for (int xx = 0; xx < 16; ++xx) s += base[yy * 16 + xx];
    float a = s * ((1.0f / 16.0f) * (1.0f / 16.0f));
    ushort uh, um, ul;
    split3(a, &uh, &um, &ul);
    rh[(size_t)n * 32 + c] = uh;
    rm[(size_t)n * 32 + c] = um;
    rl[(size_t)n * 32 + c] = ul;
  }
}

// --------------------------- NN search -------------------------------------
template<int R>
__global__ __launch_bounds__(256) void k_nn(const ushort* __restrict__ rest_h,
                                            const ushort* __restrict__ rest_m,
                                            const ushort* __restrict__ rest_l,
                                            const ushort* __restrict__ emb_h,
                                            const ushort* __restrict__ emb_m,
                                            const ushort* __restrict__ emb_l,
                                            const float* __restrict__ esq_g,
                                            float* __restrict__ pdist,
                                            int* __restrict__ pidx,
                                            int rows, int S, int cps) {
  __shared__ ushort lb[3][3][2048];
  __shared__ float les[3][64];
  const int t = threadIdx.x;
  const int w = t >> 6;
  const int col = t & 15;
  const int g = (t >> 4) & 3;
  const int sp = blockIdx.y;
  const int rowbase = blockIdx.x * (64 * R);

  auto stage = [&](int bf, int ch) {
    int cb = sp * cps + ch * 64;
    int code = cb + (t >> 2);
    int u = (t & 3) ^ ((code ^ (code >> 2)) & 3);
    size_t off = (size_t)code * 32 + (size_t)u * 8;
    gl_lds16(emb_h + off, &lb[bf][0][w * 512]);
    gl_lds16(emb_m + off, &lb[bf][1][w * 512]);
    gl_lds16(emb_l + off, &lb[bf][2][w * 512]);
    if ((t & 63) < 16) gl_lds4(esq_g + cb + w * 16 + (t & 15), &les[bf][w * 16]);
  };

  const int NC = cps >> 6;
  stage(0, 0);

  short8_t ah[R], am[R], al[R];
#pragma unroll
  for (int rt = 0; rt < R; ++rt) {
    int n = rowbase + (w * R + rt) * 16 + col;
    if (n >= rows) n = rows - 1;
    size_t o = (size_t)n * 32 + g * 8;
    ah[rt] = *(const short8_t*)(rest_h + o);
    am[rt] = *(const short8_t*)(rest_m + o);
    al[rt] = *(const short8_t*)(rest_l + o);
  }

  if (NC > 1) stage(1, 1);

  float best[R][4];
  int bidx[R][4];
#pragma unroll
  for (int rt = 0; rt < R; ++rt)
#pragma unroll
    for (int r = 0; r < 4; ++r) { best[rt][r] = -3.4e38f; bidx[rt][r] = 0x7fffffff; }

  int buf = 0;
  for (int ch = 0; ch < NC; ++ch) {
    if (ch + 2 < NC) {
      stage((ch + 2) % 3, ch + 2);
      asm volatile("s_waitcnt vmcnt(8)" ::: "memory");
    } else if (ch + 1 < NC) {
      asm volatile("s_waitcnt vmcnt(4)" ::: "memory");
    } else {
      asm volatile("s_waitcnt vmcnt(0)" ::: "memory");
    }
    __builtin_amdgcn_s_barrier();

    int cb0 = sp * cps + ch * 64;
#pragma unroll
    for (int s4 = 0; s4 < 4; ++s4) {
      int cl = s4 * 16 + col;
      int slotbase = (cl * 4 + (g ^ ((cl ^ (cl >> 2)) & 3))) * 8;
      short8_t bh  = *(const short8_t*)&lb[buf][0][slotbase];
      short8_t bm  = *(const short8_t*)&lb[buf][1][slotbase];
      short8_t bl2 = *(const short8_t*)&lb[buf][2][slotbase];
      float es = les[buf][cl];
      f32x4 c0 = {es, es, es, es};
      f32x4 acc[R];
      __builtin_amdgcn_s_setprio(1);
#pragma unroll
      for (int rt = 0; rt < R; ++rt) acc[rt] = MFMA(ah[rt], bh, c0);
#pragma unroll
      for (int rt = 0; rt < R; ++rt) acc[rt] = MFMA(ah[rt], bm, acc[rt]);
#pragma unroll
      for (int rt = 0; rt < R; ++rt) acc[rt] = MFMA(am[rt], bh, acc[rt]);
#pragma unroll
      for (int rt = 0; rt < R; ++rt) acc[rt] = MFMA(ah[rt], bl2, acc[rt]);
#pragma unroll
      for (int rt = 0; rt < R; ++rt) acc[rt] = MFMA(am[rt], bm, acc[rt]);
#pragma unroll
      for (int rt = 0; rt < R; ++rt) acc[rt] = MFMA(al[rt], bh, acc[rt]);
      __builtin_amdgcn_s_setprio(0);
      int code = cb0 + cl;
#pragma unroll
      for (int rt = 0; rt < R; ++rt)
#pragma unroll
        for (int r = 0; r < 4; ++r)
          if (acc[rt][r] > best[rt][r]) { best[rt][r] = acc[rt][r]; bidx[rt][r] = code; }
    }
    __syncthreads();
    buf = (buf + 1) % 3;
  }

#pragma unroll
  for (int rt = 0; rt < R; ++rt)
#pragma unroll
    for (int r = 0; r < 4; ++r) {
      float bd = best[rt][r];
      int bi = bidx[rt][r];
#pragma unroll
      for (int mm2 = 1; mm2 < 16; mm2 <<= 1) {
        float od = __shfl_xor(bd, mm2, 16);
        int oi = __shfl_xor(bi, mm2, 16);
        if (od > bd || (od == bd && oi < bi)) { bd = od; bi = oi; }
      }
      if ((t & 15) == 0) {
        int rown = rowbase + (w * R + rt) * 16 + g * 4 + r;
        if (rown < rows) {
          pdist[(size_t)rown * S + sp] = bd;
          pidx[(size_t)rown * S + sp] = bi;
        }
      }
    }
}

// --------------------------- fused per-scale kernel -------------------------
// grid (B,2), 1024 thr (16 waves), 16 out-ch per block, wave w = image row w.
template<bool LAST>
__global__ __launch_bounds__(1024) void k_scale(const float* __restrict__ pdist,
                                                const int* __restrict__ pidx,
                                                const float* __restrict__ emb,
                                                const float* __restrict__ tw,
                                                const int* __restrict__ ti,
                                                const ushort* __restrict__ wspl,
                                                const float* __restrict__ bias,
                                                const float* __restrict__ f,
                                                const float* __restrict__ fr_in,
                                                float* __restrict__ fr_out,
                                                float* __restrict__ fhat_out,
                                                float* __restrict__ out_idx_f,
                                                float* __restrict__ lossp,
                                                ushort* __restrict__ rh,
                                                ushort* __restrict__ rm,
                                                ushort* __restrict__ rl,
                                                int S, int pn, int si, int pn_next) {
  __shared__ ushort h_bf[3][256][40];      // 61440 B; hsm [32][176] aliased on top
  __shared__ float xt[32][208];            // 26624 B; pool-buf [16][256] aliased
  __shared__ float h_my[16][260];          // 16640 B
  __shared__ ushort w_lds[27][16][36];     // 31104 B (bank-conflict-free padded)
  __shared__ int ci_s[256];
  __shared__ float redw[16];
  float* hsm = (float*)&h_bf[0][0][0];
  float* poolb = &xt[0][0];

  const int b = blockIdx.x;
  const int cog = blockIdx.y * 16;
  const int t = threadIdx.x;
  const int pn2 = pn * pn;

  // ---- 1a. stage weights (16 out-ch slice) into padded LDS
  for (int i = t; i < 1728; i += 1024) {
    int seg = i & 3;
    int o = (i >> 2) & 15;
    int lq = i >> 6;              // 0..26 = lv*9 + q
    const ushort* src = wspl + ((size_t)lq * 32 + cog + o) * 32 + seg * 8;
    *(short8_t*)&w_lds[lq][o][seg * 8] = *(const short8_t*)src;
  }

  // ---- 1b. combine split partials -> codes (+ idx output)
  for (int rem = t; rem < pn2; rem += 1024) {
    const float* pd = pdist + (size_t)(b * pn2 + rem) * S;
    const int* pi = pidx + (size_t)(b * pn2 + rem) * S;
    float bd = pd[0]; int bi = pi[0];
    for (int s = 1; s < S; ++s) {
      float d = pd[s]; int i2 = pi[s];
      if (d > bd || (d == bd && i2 < bi)) { bd = d; bi = i2; }
    }
    ci_s[rem] = bi;
    out_idx_f[b * pn2 + rem] = (float)bi;
  }
  __syncthreads();

  // ---- 2-4. build h (f32 for my 16 ch, bf16x3 for all 32 ch)
  if (LAST) {
    for (int i = t; i < 8192; i += 1024) {
      int pix = i & 255, c = i >> 8;
      float v = emb[(size_t)ci_s[pix] * 32 + c];
      ushort uh, um, ul; split3(v, &uh, &um, &ul);
      h_bf[0][pix][c] = uh; h_bf[1][pix][c] = um; h_bf[2][pix][c] = ul;
      int cl = c - cog;
      if ((unsigned)cl < 16u) h_my[cl][pix] = v;
    }
  } else {
    for (int i = t; i < 32 * pn2; i += 1024) {
      int c = i & 31, rem = i >> 5;
      hsm[c * 176 + rem] = emb[(size_t)ci_s[rem] * 32 + c];
    }
    __syncthreads();
    int e1 = 32 * pn * 16;
    for (int i = t; i < e1; i += 1024) {
      int X = i & 15, r2 = i >> 4;
      int y = r2 % pn, c = r2 / pn;
      float a = 0.f;
#pragma unroll
      for (int u = 0; u < 4; ++u)
        a += tw[si * 64 + X * 4 + u] * hsm[c * 176 + y * pn + ti[si * 64 + X * 4 + u]];
      xt[c][y * 16 + X] = a;
    }
    __syncthreads();
    for (int i = t; i < 8192; i += 1024) {
      int pix = i & 255, c = i >> 8;
      int X = pix & 15, Y = pix >> 4;
      float a = 0.f;
#pragma unroll
      for (int u = 0; u < 4; ++u)
        a += tw[si * 64 + Y * 4 + u] * xt[c][ti[si * 64 + Y * 4 + u] * 16 + X];
      ushort uh, um, ul; split3(a, &uh, &um, &ul);
      h_bf[0][pix][c] = uh; h_bf[1][pix][c] = um; h_bf[2][pix][c] = ul;
      int cl = c - cog;
      if ((unsigned)cl < 16u) h_my[cl][pix] = a;
    }
  }
  __syncthreads();

  // ---- 5. conv via MFMA. wave w owns image row w.
  const int w = t >> 6, l = t & 63;
  const int X = l & 15, kq = l >> 4;
  const int pix = w * 16 + X;

  // prefetch f_rest (+f) RMW operands — latency hides under MFMAs
  float fr_old[4], f_old[4];
#pragma unroll
  for (int r = 0; r < 4; ++r) {
    size_t ga = ((size_t)b * 32 + cog + kq * 4 + r) * 256 + pix;
    fr_old[r] = fr_in[ga];
    f_old[r] = LAST ? f[ga] : 0.f;
  }

  f32x4 accA, accB;
#pragma unroll
  for (int r = 0; r < 4; ++r) {
    accA[r] = bias[cog + kq * 4 + r];
    accB[r] = 0.f;
  }

  for (int dy = 0; dy < 3; ++dy) {
    int Yp = w + dy - 1;
    bool ok = (Yp >= 0 && Yp < 16);
    short8_t bc[3];
    if (ok) {
#pragma unroll
      for (int lv = 0; lv < 3; ++lv)
        bc[lv] = *(const short8_t*)&h_bf[lv][Yp * 16 + X][kq * 8];
    }
#pragma unroll
    for (int dx = 0; dx < 3; ++dx) {
      int q = dy * 3 + dx;
      short8_t aH = *(const short8_t*)&w_lds[0 * 9 + q][l & 15][kq * 8];
      short8_t aM = *(const short8_t*)&w_lds[9 + q][l & 15][kq * 8];
      short8_t aL = *(const short8_t*)&w_lds[18 + q][l & 15][kq * 8];
      if (!ok) continue;
      short8_t bH = bc[0], bM = bc[1], bL = bc[2];
      if (dx == 0) { bH = s8_from_laneM1(bH); bM = s8_from_laneM1(bM); bL = s8_from_laneM1(bL); }
      else if (dx == 2) { bH = s8_from_laneP1(bH); bM = s8_from_laneP1(bM); bL = s8_from_laneP1(bL); }
      accA = MFMA(aH, bH, accA);
      accB = MFMA(aH, bM, accB);
      accA = MFMA(aM, bH, accA);
      accB = MFMA(aH, bL, accB);
      accA = MFMA(aM, bM, accA);
      accB = MFMA(aL, bH, accB);
    }
  }

  // ---- 6. epilogue: residual mix, f_rest RMW, loss, pool staging
  float lsum = 0.f;
#pragma unroll
  for (int r = 0; r < 4; ++r) {
    int ol = kq * 4 + r;
    float convv = accA[r] + accB[r];
    float outv = 0.5f * h_my[ol][pix] + 0.5f * convv;
    float nf = fr_old[r] - outv;
    size_t ga = ((size_t)b * 32 + cog + ol) * 256 + pix;
    if (LAST) {
      fhat_out[ga] = f_old[r] - nf;
    } else {
      fr_out[ga] = nf;
      poolb[ol * 256 + pix] = nf;
    }
    lsum += nf * nf;
  }

  // ---- 7. pool updated residual for next scale's NN input
  if (!LAST) {
    __syncthreads();
    int pn2n = pn_next * pn_next;
    for (int i = t; i < 16 * pn2n; i += 1024) {
      int o = i / pn2n, rem = i - o * pn2n;
      int y = rem / pn_next, x = rem - y * pn_next;
      int sy = (y * 16) / pn_next, ey = ((y + 1) * 16 + pn_next - 1) / pn_next;
      int sx = (x * 16) / pn_next, ex = ((x + 1) * 16 + pn_next - 1) / pn_next;
      float s = 0.f;
      for (int yy = sy; yy < ey; ++yy)
        for (int xx = sx; xx < ex; ++xx) s += poolb[o * 256 + yy * 16 + xx];
      float a = s * ((1.0f / (float)(ey - sy)) * (1.0f / (float)(ex - sx)));
      ushort uh, um, ul;
      split3(a, &uh, &um, &ul);
      size_t n = (size_t)b * pn2n + rem;
      rh[n * 32 + cog + o] = uh;
      rm[n * 32 + cog + o] = um;
      rl[n * 32 + cog + o] = ul;
    }
  }

  // ---- 8. loss partial
#pragma unroll
  for (int off = 32; off > 0; off >>= 1) lsum += __shfl_down(lsum, off);
  if (l == 0) redw[w] = lsum;
  __syncthreads();
  if (t == 0) {
    float s2 = 0.f;
#pragma unroll
    for (int i = 0; i < 16; ++i) s2 += redw[i];
    lossp[si * 256 + blockIdx.y * 128 + b] = s2;
  }
}

__global__ __launch_bounds__(256) void k_lossfin(const float* __restrict__ part,
                                                 float* __restrict__ out) {
  int t = threadIdx.x;
  float s = 0.f;
  for (int i = t; i < SN_ * 256; i += 256) s += part[i];
  __shared__ float red[256];
  red[t] = s;
  __syncthreads();
  for (int o = 128; o > 0; o >>= 1) {
    if (t < o) red[t] += red[t + o];
    __syncthreads();
  }
  if (t == 0) out[NPIX_] = red[0] * (1.25f / (10.0f * (float)NPIX_));
}

// --------------------------- host side -------------------------------------

static void compute_phi_k(int* ks) {
  const int K = 4;
  double start = 1.0 / (3.0 * K);
  double stop = 1.0 - 1.0 / (3.0 * K);
  double step = (stop - start) / (K - 1);
  double ticks[4];
  for (int i = 0; i < K; ++i) ticks[i] = (double)i * step + start;
  ticks[K - 1] = stop;
  for (int si = 0; si < SN_; ++si) {
    double x = (double)si / (SN_ - 1);
    int best = 0;
    double bd = fabs(ticks[0] - x);
    for (int i = 1; i < K; ++i) {
      double d = fabs(ticks[i] - x);
      if (d < bd) { bd = d; best = i; }
    }
    ks[si] = best;
  }
}

extern "C" void kernel_launch(void* const* d_in, const int* in_sizes, int n_in,
                              void* d_out, int out_size, void* d_ws, size_t ws_size,
                              hipStream_t stream) {
  (void)in_sizes; (void)n_in; (void)out_size; (void)ws_size;
  const float* f    = (const float*)d_in[0];
  const float* emb  = (const float*)d_in[1];
  const float* phiW = (const float*)d_in[2];
  const float* phiB = (const float*)d_in[3];
  float* out = (float*)d_out;
  float* ws = (float*)d_ws;

  float* f_rest = ws + WS_FREST;
  float* pdist  = ws + WS_PD;
  int*   pidx   = (int*)(ws + WS_PI);
  float* esq    = ws + WS_ESQ;
  float* tw     = ws + WS_TW;
  int*   ti     = (int*)(ws + WS_TI);
  float* lossp  = ws + WS_LOSSP;
  ushort* rest_h = (ushort*)(ws + WS_RESTH);
  ushort* rest_m = (ushort*)(ws + WS_RESTM);
  ushort* rest_l = (ushort*)(ws + WS_RESTL);
  ushort* emb_h  = (ushort*)(ws + WS_EMBH);
  ushort* emb_m  = (ushort*)(ws + WS_EMBM);
  ushort* emb_l  = (ushort*)(ws + WS_EMBL);
  ushort* wspl   = (ushort*)(ws + WS_WSPL);

  static const int pns[SN_] = {1, 2, 3, 4, 5, 6, 8, 10, 13, 16};
  static const int Rs[SN_]  = {1, 1, 1, 1, 2, 2, 4, 4, 4, 4};
  static const int Ss[SN_]  = {64, 64, 64, 64, 64, 64, 32, 32, 16, 16};
  int ks[SN_];
  compute_phi_k(ks);

  k_prep<<<49, 256, 0, stream>>>(emb, f, phiW, esq, emb_h, emb_m, emb_l, tw, ti,
                                 rest_h, rest_m, rest_l, wspl);

  int idx_off = 0;
  for (int si = 0; si < SN_; ++si) {
    int pn = pns[si];
    int pn2 = pn * pn;
    int rows = B_ * pn2;
    int R = Rs[si], S = Ss[si];
    int cps = V_ / S;
    int rowblocks = (rows + 64 * R - 1) / (64 * R);

    dim3 grid(rowblocks, S);
    if (R == 1)
      k_nn<1><<<grid, 256, 0, stream>>>(rest_h, rest_m, rest_l, emb_h, emb_m, emb_l,
                                        esq, pdist, pidx, rows, S, cps);
    else if (R == 2)
      k_nn<2><<<grid, 256, 0, stream>>>(rest_h, rest_m, rest_l, emb_h, emb_m, emb_l,
                                        esq, pdist, pidx, rows, S, cps);
    else
      k_nn<4><<<grid, 256, 0, stream>>>(rest_h, rest_m, rest_l, emb_h, emb_m, emb_l,
                                        esq, pdist, pidx, rows, S, cps);

    bool last = (si == SN_ - 1);
    int pn_next = last ? 0 : pns[si + 1];
    const ushort* wsp = wspl + (size_t)ks[si] * 27648;
    const float* bi = phiB + (size_t)ks[si] * 32;
    if (last)
      k_scale<true><<<dim3(B_, 2), 1024, 0, stream>>>(
          pdist, pidx, emb, tw, ti, wsp, bi, f,
          f_rest, f_rest, out,
          out + NPIX_ + 1 + idx_off, lossp,
          rest_h, rest_m, rest_l, S, pn, si, pn_next);
    else
      k_scale<false><<<dim3(B_, 2), 1024, 0, stream>>>(
          pdist, pidx, emb, tw, ti, wsp, bi, f,
          (si == 0) ? f : f_rest, f_rest, nullptr,
          out + NPIX_ + 1 + idx_off, lossp,
          rest_h, rest_m, rest_l, S, pn, si, pn_next);
    idx_off += rows;
  }

  k_lossfin<<<1, 256, 0, stream>>>(lossp, out);
}

// Round 7
// 390.071 us; speedup vs baseline: 1.1882x; 1.1882x over previous
//
#include <hip/hip_runtime.h>
#include <hip/hip_bf16.h>
#include <math.h>

// ---------------------------------------------------------------------------
// VAR quantizer forward. Round 7: k_nn reverted to round-3 best config
// (2-buffer, NC-deep, no setprio) + packed-u64 atomicMax argmin writeback;
// k_scale wave-owned-channel pipeline (3 barriers), early fr prefetch,
// ping-pong slot zeroing. Conv/NN arithmetic bitwise-identical to round 5/6.
// Output: [f_hat 1048576][loss 1][idx-as-float 87040]
// ---------------------------------------------------------------------------

#define B_  128
#define V_  4096
#define SN_ 10
#define NPIX_ (B_*32*256)   // 1048576

// ws layout (float offsets)
#define WS_FREST   0
#define WS_SLOTA   1048576   // 32768 ull
#define WS_SLOTB   1114112
#define WS_ESQ     1179648
#define WS_TW      1183744
#define WS_TI      1184320
#define WS_LOSSP   1184896
#define WS_RESTH   1187456
#define WS_RESTM   1711744
#define WS_RESTL   2236032
#define WS_EMBH    2760320
#define WS_EMBM    2825856
#define WS_EMBL    2891392
#define WS_WSPL    2956928
// end 3012224 floats = 11.5 MB

typedef __attribute__((ext_vector_type(8))) short short8_t;
typedef __attribute__((ext_vector_type(4))) float f32x4;
typedef unsigned long long ull;
#define MFMA(a,b,c) __builtin_amdgcn_mfma_f32_16x16x32_bf16((a),(b),(c),0,0,0)

__device__ inline void gl_lds16(const void* g, void* l) {
  __builtin_amdgcn_global_load_lds((const __attribute__((address_space(1))) void*)g,
                                   (__attribute__((address_space(3))) void*)l, 16, 0, 0);
}
__device__ inline void gl_lds4(const void* g, void* l) {
  __builtin_amdgcn_global_load_lds((const __attribute__((address_space(1))) void*)g,
                                   (__attribute__((address_space(3))) void*)l, 4, 0, 0);
}

// split f32 -> 3 truncated bf16 levels (captures ~24 bits)
__device__ inline void split3(float a, ushort* h, ushort* m, ushort* l) {
  unsigned ua = __float_as_uint(a);
  ushort uh = (ushort)(ua >> 16);
  float fh = __uint_as_float((unsigned)uh << 16);
  float r1 = a - fh;
  ushort um = (ushort)(__float_as_uint(r1) >> 16);
  float fm = __uint_as_float((unsigned)um << 16);
  float r2 = r1 - fm;
  ushort ul = (ushort)(__float_as_uint(r2) >> 16);
  *h = uh; *m = um; *l = ul;
}

// DPP lane shifts within 16-lane rows; bound_ctrl=1 -> zero fill (SAME pad)
__device__ inline short8_t s8_from_laneM1(short8_t v) {
  union { short8_t s; unsigned u[4]; } a, r;
  a.s = v;
#pragma unroll
  for (int i = 0; i < 4; ++i)
    r.u[i] = __builtin_amdgcn_update_dpp(0u, a.u[i], 0x111, 0xF, 0xF, true);
  return r.s;
}
__device__ inline short8_t s8_from_laneP1(short8_t v) {
  union { short8_t s; unsigned u[4]; } a, r;
  a.s = v;
#pragma unroll
  for (int i = 0; i < 4; ++i)
    r.u[i] = __builtin_amdgcn_update_dpp(0u, a.u[i], 0x101, 0xF, 0xF, true);
  return r.s;
}

// --------------------------- prep kernels -----------------------------------

__global__ __launch_bounds__(256) void k_prep(const float* __restrict__ emb,
                                              float* __restrict__ esq,
                                              ushort* __restrict__ eh,
                                              ushort* __restrict__ em,
                                              ushort* __restrict__ el,
                                              float* __restrict__ tw,
                                              int* __restrict__ ti,
                                              ull* __restrict__ slotA) {
  int bx = blockIdx.x, t = threadIdx.x;
  if (bx < 16) {
    int v = bx * 256 + t;
    const float4* e4 = (const float4*)(emb + (size_t)v * 32);
    float s = 0.f;
#pragma unroll
    for (int half = 0; half < 4; ++half) {
      float4 x0 = e4[half * 2], x1 = e4[half * 2 + 1];
      s += x0.x * x0.x + x0.y * x0.y + x0.z * x0.z + x0.w * x0.w;
      s += x1.x * x1.x + x1.y * x1.y + x1.z * x1.z + x1.w * x1.w;
      float xs[8] = {x0.x, x0.y, x0.z, x0.w, x1.x, x1.y, x1.z, x1.w};
      ushort hs[8], ms[8], ls[8];
#pragma unroll
      for (int j = 0; j < 8; ++j) split3(xs[j], &hs[j], &ms[j], &ls[j]);
      uint4 ph, pm, pl;
      ph.x = (unsigned)hs[0] | ((unsigned)hs[1] << 16); ph.y = (unsigned)hs[2] | ((unsigned)hs[3] << 16);
      ph.z = (unsigned)hs[4] | ((unsigned)hs[5] << 16); ph.w = (unsigned)hs[6] | ((unsigned)hs[7] << 16);
      pm.x = (unsigned)ms[0] | ((unsigned)ms[1] << 16); pm.y = (unsigned)ms[2] | ((unsigned)ms[3] << 16);
      pm.z = (unsigned)ms[4] | ((unsigned)ms[5] << 16); pm.w = (unsigned)ms[6] | ((unsigned)ms[7] << 16);
      pl.x = (unsigned)ls[0] | ((unsigned)ls[1] << 16); pl.y = (unsigned)ls[2] | ((unsigned)ls[3] << 16);
      pl.z = (unsigned)ls[4] | ((unsigned)ls[5] << 16); pl.w = (unsigned)ls[6] | ((unsigned)ls[7] << 16);
      ((uint4*)(eh + (size_t)v * 32))[half] = ph;
      ((uint4*)(em + (size_t)v * 32))[half] = pm;
      ((uint4*)(el + (size_t)v * 32))[half] = pl;
    }
    esq[v] = -0.5f * s;
  } else {
    if (t < 128) slotA[t] = 0ULL;     // si=0 argmax slots
    if (t >= 144) return;
    const int pns[9] = {1, 2, 3, 4, 5, 6, 8, 10, 13};
    int si = t / 16, Y = t % 16;
    int pn = pns[si];
    double src = (Y + 0.5) * (double)pn / 16.0 - 0.5;
    double fl = floor(src);
    const double a = -0.75;
#pragma unroll
    for (int k = 0; k < 4; ++k) {
      double x = fabs(src - (fl + (k - 1)));
      double w;
      if (x <= 1.0)      w = (a + 2.0) * x * x * x - (a + 3.0) * x * x + 1.0;
      else if (x < 2.0)  w = a * x * x * x - 5.0 * a * x * x + 8.0 * a * x - 4.0 * a;
      else               w = 0.0;
      int id = (int)fl + (k - 1);
      id = id < 0 ? 0 : (id > pn - 1 ? pn - 1 : id);
      tw[si * 64 + Y * 4 + k] = (float)w;
      ti[si * 64 + Y * 4 + k] = id;
    }
  }
}

__global__ __launch_bounds__(256) void k_prep2(const float* __restrict__ f,
                                               const float* __restrict__ phiW,
                                               ushort* __restrict__ rh,
                                               ushort* __restrict__ rm,
                                               ushort* __restrict__ rl,
                                               ushort* __restrict__ wspl) {
  int bx = blockIdx.x, t = threadIdx.x;
  if (bx < 16) {
    // phi weight split: wspl[phi][lvl*9+q][o][ci]
    int i = bx * 256 + t;   // 4096 (phi,o,ci)
    int phi = i >> 10, o = (i >> 5) & 31, ci = i & 31;
    const float* src = phiW + (((size_t)phi * 32 + o) * 32 + ci) * 9;
    ushort* dst = wspl + (size_t)phi * 27648;
#pragma unroll
    for (int q = 0; q < 9; ++q) {
      ushort uh, um, ul;
      split3(src[q], &uh, &um, &ul);
      dst[(size_t)(0 * 9 + q) * 1024 + o * 32 + ci] = uh;
      dst[(size_t)(9 + q) * 1024 + o * 32 + ci] = um;
      dst[(size_t)(18 + q) * 1024 + o * 32 + ci] = ul;
    }
  } else {
    // si=0 NN input: area-pool f to 1x1 -> [n][c] 3-level bf16
    int tid = (bx - 16) * 256 + t;   // 4096
    int c = tid & 31, n = tid >> 5;
    const float* base = f + ((size_t)n * 32 + c) * 256;
    float s = 0.f;
    for (int yy = 0; yy < 16; ++yy)
      for (int xx = 0; xx < 16; ++xx) s += base[yy * 16 + xx];
    float a = s * ((1.0f / 16.0f) * (1.0f / 16.0f));
    ushort uh, um, ul;
    split3(a, &uh, &um, &ul);
    rh[(size_t)n * 32 + c] = uh;
    rm[(size_t)n * 32 + c] = um;
    rl[(size_t)n * 32 + c] = ul;
  }
}

// --------------------------- NN search (round-3 body + atomic epilogue) -----
template<int R>
__global__ __launch_bounds__(256) void k_nn(const ushort* __restrict__ rest_h,
                                            const ushort* __restrict__ rest_m,
                                            const ushort* __restrict__ rest_l,
                                            const ushort* __restrict__ emb_h,
                                            const ushort* __restrict__ emb_m,
                                            const ushort* __restrict__ emb_l,
                                            const float* __restrict__ esq_g,
                                            ull* __restrict__ slot,
                                            int rows, int S, int cps) {
  __shared__ ushort lb[2][3][2048];
  __shared__ float les[2][64];
  const int t = threadIdx.x;
  const int w = t >> 6;
  const int col = t & 15;
  const int g = (t >> 4) & 3;
  const int sp = blockIdx.y;
  const int rowbase = blockIdx.x * (64 * R);

  auto stage = [&](int bf, int ch) {
    int cb = sp * cps + ch * 64;
    int code = cb + (t >> 2);
    int u = (t & 3) ^ ((code ^ (code >> 2)) & 3);
    size_t off = (size_t)code * 32 + (size_t)u * 8;
    gl_lds16(emb_h + off, &lb[bf][0][w * 512]);
    gl_lds16(emb_m + off, &lb[bf][1][w * 512]);
    gl_lds16(emb_l + off, &lb[bf][2][w * 512]);
    if ((t & 63) < 16) gl_lds4(esq_g + cb + w * 16 + (t & 15), &les[bf][w * 16]);
  };

  stage(0, 0);

  short8_t ah[R], am[R], al[R];
#pragma unroll
  for (int rt = 0; rt < R; ++rt) {
    int n = rowbase + (w * R + rt) * 16 + col;
    if (n >= rows) n = rows - 1;
    size_t o = (size_t)n * 32 + g * 8;
    ah[rt] = *(const short8_t*)(rest_h + o);
    am[rt] = *(const short8_t*)(rest_m + o);
    al[rt] = *(const short8_t*)(rest_l + o);
  }

  float best[R][4];
  int bidx[R][4];
#pragma unroll
  for (int rt = 0; rt < R; ++rt)
#pragma unroll
    for (int r = 0; r < 4; ++r) { best[rt][r] = -3.4e38f; bidx[rt][r] = 0x7fffffff; }

  const int NC = cps >> 6;
  int buf = 0;
  for (int ch = 0; ch < NC; ++ch) {
    if (ch + 1 < NC) {
      stage(buf ^ 1, ch + 1);
      asm volatile("s_waitcnt vmcnt(4)" ::: "memory");
    } else {
      asm volatile("s_waitcnt vmcnt(0)" ::: "memory");
    }
    __builtin_amdgcn_s_barrier();

    int cb0 = sp * cps + ch * 64;
#pragma unroll
    for (int s4 = 0; s4 < 4; ++s4) {
      int cl = s4 * 16 + col;
      int slotbase = (cl * 4 + (g ^ ((cl ^ (cl >> 2)) & 3))) * 8;
      short8_t bh  = *(const short8_t*)&lb[buf][0][slotbase];
      short8_t bm  = *(const short8_t*)&lb[buf][1][slotbase];
      short8_t bl2 = *(const short8_t*)&lb[buf][2][slotbase];
      float es = les[buf][cl];
      f32x4 c0 = {es, es, es, es};
      f32x4 acc[R];
      // per-acc order identical to rounds 2-6: hh,hm,mh,hl,mm,lh
#pragma unroll
      for (int rt = 0; rt < R; ++rt) acc[rt] = MFMA(ah[rt], bh, c0);
#pragma unroll
      for (int rt = 0; rt < R; ++rt) acc[rt] = MFMA(ah[rt], bm, acc[rt]);
#pragma unroll
      for (int rt = 0; rt < R; ++rt) acc[rt] = MFMA(am[rt], bh, acc[rt]);
#pragma unroll
      for (int rt = 0; rt < R; ++rt) acc[rt] = MFMA(ah[rt], bl2, acc[rt]);
#pragma unroll
      for (int rt = 0; rt < R; ++rt) acc[rt] = MFMA(am[rt], bm, acc[rt]);
#pragma unroll
      for (int rt = 0; rt < R; ++rt) acc[rt] = MFMA(al[rt], bh, acc[rt]);
      int code = cb0 + cl;
#pragma unroll
      for (int rt = 0; rt < R; ++rt)
#pragma unroll
        for (int r = 0; r < 4; ++r)
          if (acc[rt][r] > best[rt][r]) { best[rt][r] = acc[rt][r]; bidx[rt][r] = code; }
    }
    __syncthreads();
    buf ^= 1;
  }

  // 16-lane reduce then one packed atomicMax per row:
  // key = (monotone(acc) << 32) | ~idx  ==  max acc, tie -> min idx
#pragma unroll
  for (int rt = 0; rt < R; ++rt)
#pragma unroll
    for (int r = 0; r < 4; ++r) {
      float bd = best[rt][r];
      int bi = bidx[rt][r];
#pragma unroll
      for (int mm2 = 1; mm2 < 16; mm2 <<= 1) {
        float od = __shfl_xor(bd, mm2, 16);
        int oi = __shfl_xor(bi, mm2, 16);
        if (od > bd || (od == bd && oi < bi)) { bd = od; bi = oi; }
      }
      if ((t & 15) == 0) {
        int rown = rowbase + (w * R + rt) * 16 + g * 4 + r;
        if (rown < rows) {
          unsigned mu = __float_as_uint(bd);
          mu ^= (mu & 0x80000000u) ? 0xFFFFFFFFu : 0x80000000u;
          ull key = ((ull)mu << 32) | (unsigned)(~bi);
          atomicMax(&slot[rown], key);
        }
      }
    }
}

// --------------------------- fused per-scale kernel -------------------------
template<bool LAST>
__global__ __launch_bounds__(1024) void k_scale(const ull* __restrict__ slot_in,
                                                ull* __restrict__ slot_next,
                                                const float* __restrict__ emb,
                                                const float* __restrict__ tw,
                                                const int* __restrict__ ti,
                                                const ushort* __restrict__ wspl,
                                                const float* __restrict__ bias,
                                                const float* __restrict__ f,
                                                const float* __restrict__ fr_in,
                                                float* __restrict__ fr_out,
                                                float* __restrict__ fhat_out,
                                                float* __restrict__ out_idx_f,
                                                float* __restrict__ lossp,
                                                ushort* __restrict__ rh,
                                                ushort* __restrict__ rm,
                                                ushort* __restrict__ rl,
                                                int pn, int si, int pn_next,
                                                int rows_next) {
  __shared__ ushort h_bf[3][256][40];      // 61440 B
  __shared__ float hsm[32 * 177];          // 22656 B (poolb later)
  __shared__ float xt[32][208];            // 26624 B
  __shared__ float h_my[16][260];          // 16640 B
  __shared__ ushort w_lds[27][16][36];     // 31104 B
  __shared__ int ci_s[256];
  __shared__ float redw[16];
  float* poolb = hsm;

  const int b = blockIdx.x;
  const int cog = blockIdx.y * 16;
  const int t = threadIdx.x;
  const int pn2 = pn * pn;
  const int w = t >> 6, l = t & 63;
  const int X = l & 15, kq = l >> 4;
  const int pix = w * 16 + X;

  // ---- phase 0: early fr prefetch (consumed in phase 2)
  float fr_old[4], f_old[4];
#pragma unroll
  for (int r = 0; r < 4; ++r) {
    size_t ga = ((size_t)b * 32 + cog + kq * 4 + r) * 256 + pix;
    fr_old[r] = fr_in[ga];
    f_old[r] = LAST ? f[ga] : 0.f;
  }
  for (int i = t; i < 1728; i += 1024) {
    int seg = i & 3;
    int o = (i >> 2) & 15;
    int lq = i >> 6;
    const ushort* src = wspl + ((size_t)lq * 32 + cog + o) * 32 + seg * 8;
    *(short8_t*)&w_lds[lq][o][seg * 8] = *(const short8_t*)src;
  }
  for (int rem = t; rem < pn2; rem += 1024) {
    ull sv = slot_in[b * pn2 + rem];
    int code = (int)(~(unsigned)sv);
    ci_s[rem] = code;
    out_idx_f[b * pn2 + rem] = (float)code;
  }
  __syncthreads();

  // ---- phase 1: wave w owns channels {2w, 2w+1} end-to-end
#pragma unroll
  for (int cc = 0; cc < 2; ++cc) {
    int c = 2 * w + cc;
    if (LAST) {
      for (int p2 = l; p2 < 256; p2 += 64) {
        float v = emb[(size_t)ci_s[p2] * 32 + c];
        ushort uh, um, ul; split3(v, &uh, &um, &ul);
        h_bf[0][p2][c] = uh; h_bf[1][p2][c] = um; h_bf[2][p2][c] = ul;
        int cl = c - cog;
        if ((unsigned)cl < 16u) h_my[cl][p2] = v;
      }
    } else {
      for (int rem = l; rem < pn2; rem += 64)
        hsm[c * 177 + rem] = emb[(size_t)ci_s[rem] * 32 + c];
      asm volatile("s_waitcnt lgkmcnt(0)" ::: "memory");
      for (int i = l; i < pn * 16; i += 64) {
        int Xi = i & 15, y = i >> 4;
        float a = 0.f;
#pragma unroll
        for (int u = 0; u < 4; ++u)
          a += tw[si * 64 + Xi * 4 + u] * hsm[c * 177 + y * pn + ti[si * 64 + Xi * 4 + u]];
        xt[c][y * 16 + Xi] = a;
      }
      asm volatile("s_waitcnt lgkmcnt(0)" ::: "memory");
      for (int p2 = l; p2 < 256; p2 += 64) {
        int Xi = p2 & 15, Y = p2 >> 4;
        float a = 0.f;
#pragma unroll
        for (int u = 0; u < 4; ++u)
          a += tw[si * 64 + Y * 4 + u] * xt[c][ti[si * 64 + Y * 4 + u] * 16 + Xi];
        ushort uh, um, ul; split3(a, &uh, &um, &ul);
        h_bf[0][p2][c] = uh; h_bf[1][p2][c] = um; h_bf[2][p2][c] = ul;
        int cl = c - cog;
        if ((unsigned)cl < 16u) h_my[cl][p2] = a;
      }
    }
  }
  __syncthreads();

  // ---- phase 2: conv via MFMA (wave = image row w), then epilogue
  f32x4 accA, accB;
#pragma unroll
  for (int r = 0; r < 4; ++r) {
    accA[r] = bias[cog + kq * 4 + r];
    accB[r] = 0.f;
  }

  for (int dy = 0; dy < 3; ++dy) {
    int Yp = w + dy - 1;
    bool ok = (Yp >= 0 && Yp < 16);
    short8_t bc[3];
    if (ok) {
#pragma unroll
      for (int lv = 0; lv < 3; ++lv)
        bc[lv] = *(const short8_t*)&h_bf[lv][Yp * 16 + X][kq * 8];
    }
#pragma unroll
    for (int dx = 0; dx < 3; ++dx) {
      int q = dy * 3 + dx;
      short8_t aH = *(const short8_t*)&w_lds[0 * 9 + q][l & 15][kq * 8];
      short8_t aM = *(const short8_t*)&w_lds[9 + q][l & 15][kq * 8];
      short8_t aL = *(const short8_t*)&w_lds[18 + q][l & 15][kq * 8];
      if (!ok) continue;
      short8_t bH = bc[0], bM = bc[1], bL = bc[2];
      if (dx == 0) { bH = s8_from_laneM1(bH); bM = s8_from_laneM1(bM); bL = s8_from_laneM1(bL); }
      else if (dx == 2) { bH = s8_from_laneP1(bH); bM = s8_from_laneP1(bM); bL = s8_from_laneP1(bL); }
      accA = MFMA(aH, bH, accA);
      accB = MFMA(aH, bM, accB);
      accA = MFMA(aM, bH, accA);
      accB = MFMA(aH, bL, accB);
      accA = MFMA(aM, bM, accA);
      accB = MFMA(aL, bH, accB);
    }
  }

  float lsum = 0.f;
#pragma unroll
  for (int r = 0; r < 4; ++r) {
    int ol = kq * 4 + r;
    float convv = accA[r] + accB[r];
    float outv = 0.5f * h_my[ol][pix] + 0.5f * convv;
    float nf = fr_old[r] - outv;
    size_t ga = ((size_t)b * 32 + cog + ol) * 256 + pix;
    if (LAST) {
      fhat_out[ga] = f_old[r] - nf;
    } else {
      fr_out[ga] = nf;
      poolb[ol * 256 + pix] = nf;
    }
    lsum += nf * nf;
  }

  // ---- phase 3: pool + next-slot zero + loss
  if (!LAST) {
    __syncthreads();
    int pn2n = pn_next * pn_next;
    for (int i = t; i < 16 * pn2n; i += 1024) {
      int o = i / pn2n, rem = i - o * pn2n;
      int y = rem / pn_next, x = rem - y * pn_next;
      int sy = (y * 16) / pn_next, ey = ((y + 1) * 16 + pn_next - 1) / pn_next;
      int sx = (x * 16) / pn_next, ex = ((x + 1) * 16 + pn_next - 1) / pn_next;
      float s = 0.f;
      for (int yy = sy; yy < ey; ++yy)
        for (int xx = sx; xx < ex; ++xx) s += poolb[o * 256 + yy * 16 + xx];
      float a = s * ((1.0f / (float)(ey - sy)) * (1.0f / (float)(ex - sx)));
      ushort uh, um, ul;
      split3(a, &uh, &um, &ul);
      size_t n = (size_t)b * pn2n + rem;
      rh[n * 32 + cog + o] = uh;
      rm[n * 32 + cog + o] = um;
      rl[n * 32 + cog + o] = ul;
    }
    int blk = b * 2 + blockIdx.y;                 // 0..255
    int stride = (rows_next + 255) >> 8;
    int base = blk * stride;
    for (int i = t; i < stride; i += 1024) {
      int s = base + i;
      if (s < rows_next) slot_next[s] = 0ULL;
    }
  }

#pragma unroll
  for (int off = 32; off > 0; off >>= 1) lsum += __shfl_down(lsum, off);
  if (l == 0) redw[w] = lsum;
  __syncthreads();
  if (t == 0) {
    float s2 = 0.f;
#pragma unroll
    for (int i = 0; i < 16; ++i) s2 += redw[i];
    lossp[si * 256 + blockIdx.y * 128 + b] = s2;
  }
}

__global__ __launch_bounds__(256) void k_lossfin(const float* __restrict__ part,
                                                 float* __restrict__ out) {
  int t = threadIdx.x;
  float s = 0.f;
  for (int i = t; i < SN_ * 256; i += 256) s += part[i];
  __shared__ float red[256];
  red[t] = s;
  __syncthreads();
  for (int o = 128; o > 0; o >>= 1) {
    if (t < o) red[t] += red[t + o];
    __syncthreads();
  }
  if (t == 0) out[NPIX_] = red[0] * (1.25f / (10.0f * (float)NPIX_));
}

// --------------------------- host side -------------------------------------

static void compute_phi_k(int* ks) {
  const int K = 4;
  double start = 1.0 / (3.0 * K);
  double stop = 1.0 - 1.0 / (3.0 * K);
  double step = (stop - start) / (K - 1);
  double ticks[4];
  for (int i = 0; i < K; ++i) ticks[i] = (double)i * step + start;
  ticks[K - 1] = stop;
  for (int si = 0; si < SN_; ++si) {
    double x = (double)si / (SN_ - 1);
    int best = 0;
    double bd = fabs(ticks[0] - x);
    for (int i = 1; i < K; ++i) {
      double d = fabs(ticks[i] - x);
      if (d < bd) { bd = d; best = i; }
    }
    ks[si] = best;
  }
}

extern "C" void kernel_launch(void* const* d_in, const int* in_sizes, int n_in,
                              void* d_out, int out_size, void* d_ws, size_t ws_size,
                              hipStream_t stream) {
  (void)in_sizes; (void)n_in; (void)out_size; (void)ws_size;
  const float* f    = (const float*)d_in[0];
  const float* emb  = (const float*)d_in[1];
  const float* phiW = (const float*)d_in[2];
  const float* phiB = (const float*)d_in[3];
  float* out = (float*)d_out;
  float* ws = (float*)d_ws;

  float* f_rest = ws + WS_FREST;
  ull*   slotA  = (ull*)(ws + WS_SLOTA);
  ull*   slotB  = (ull*)(ws + WS_SLOTB);
  float* esq    = ws + WS_ESQ;
  float* tw     = ws + WS_TW;
  int*   ti     = (int*)(ws + WS_TI);
  float* lossp  = ws + WS_LOSSP;
  ushort* rest_h = (ushort*)(ws + WS_RESTH);
  ushort* rest_m = (ushort*)(ws + WS_RESTM);
  ushort* rest_l = (ushort*)(ws + WS_RESTL);
  ushort* emb_h  = (ushort*)(ws + WS_EMBH);
  ushort* emb_m  = (ushort*)(ws + WS_EMBM);
  ushort* emb_l  = (ushort*)(ws + WS_EMBL);
  ushort* wspl   = (ushort*)(ws + WS_WSPL);

  static const int pns[SN_] = {1, 2, 3, 4, 5, 6, 8, 10, 13, 16};
  static const int Rs[SN_]  = {1, 1, 1, 2, 2, 2, 4, 4, 4, 4};
  static const int Ss[SN_]  = {64, 64, 32, 32, 16, 16, 16, 16, 8, 4};
  int ks[SN_];
  compute_phi_k(ks);

  k_prep<<<17, 256, 0, stream>>>(emb, esq, emb_h, emb_m, emb_l, tw, ti, slotA);
  k_prep2<<<32, 256, 0, stream>>>(f, phiW, rest_h, rest_m, rest_l, wspl);

  int idx_off = 0;
  for (int si = 0; si < SN_; ++si) {
    int pn = pns[si];
    int pn2 = pn * pn;
    int rows = B_ * pn2;
    int R = Rs[si], S = Ss[si];
    int cps = V_ / S;
    int rowblocks = (rows + 64 * R - 1) / (64 * R);
    ull* slot_cur  = (si & 1) ? slotB : slotA;
    ull* slot_nxt  = (si & 1) ? slotA : slotB;

    dim3 grid(rowblocks, S);
    if (R == 1)
      k_nn<1><<<grid, 256, 0, stream>>>(rest_h, rest_m, rest_l, emb_h, emb_m, emb_l,
                                        esq, slot_cur, rows, S, cps);
    else if (R == 2)
      k_nn<2><<<grid, 256, 0, stream>>>(rest_h, rest_m, rest_l, emb_h, emb_m, emb_l,
                                        esq, slot_cur, rows, S, cps);
    else
      k_nn<4><<<grid, 256, 0, stream>>>(rest_h, rest_m, rest_l, emb_h, emb_m, emb_l,
                                        esq, slot_cur, rows, S, cps);

    bool last = (si == SN_ - 1);
    int pn_next = last ? 0 : pns[si + 1];
    int rows_next = last ? 0 : B_ * pn_next * pn_next;
    const ushort* wsp = wspl + (size_t)ks[si] * 27648;
    const float* bi = phiB + (size_t)ks[si] * 32;
    if (last)
      k_scale<true><<<dim3(B_, 2), 1024, 0, stream>>>(
          slot_cur, slot_nxt, emb, tw, ti, wsp, bi, f,
          f_rest, f_rest, out,
          out + NPIX_ + 1 + idx_off, lossp,
          rest_h, rest_m, rest_l, pn, si, pn_next, rows_next);
    else
      k_scale<false><<<dim3(B_, 2), 1024, 0, stream>>>(
          slot_cur, slot_nxt, emb, tw, ti, wsp, bi, f,
          (si == 0) ? f : f_rest, f_rest, nullptr,
          out + NPIX_ + 1 + idx_off, lossp,
          rest_h, rest_m, rest_l, pn, si, pn_next, rows_next);
    idx_off += rows;
  }

  k_lossfin<<<1, 256, 0, stream>>>(lossp, out);
}

// Round 8
// 363.108 us; speedup vs baseline: 1.2765x; 1.0743x over previous
//
#include <hip/hip_runtime.h>
#include <hip/hip_bf16.h>
#include <math.h>

// ---------------------------------------------------------------------------
// VAR quantizer forward. Round 8: k_nn unchanged (round-7, proven 55us).
// k_scale data-movement rework: coalesced float4 emb gather (8 thr/code row),
// o-minor coalesced pool stores, 3-barrier phase chain. All per-element
// arithmetic bitwise-identical to round 7.
// Output: [f_hat 1048576][loss 1][idx-as-float 87040]
// ---------------------------------------------------------------------------

#define B_  128
#define V_  4096
#define SN_ 10
#define NPIX_ (B_*32*256)   // 1048576

// ws layout (float offsets)
#define WS_FREST   0
#define WS_SLOTA   1048576   // 32768 ull
#define WS_SLOTB   1114112
#define WS_ESQ     1179648
#define WS_TW      1183744
#define WS_TI      1184320
#define WS_LOSSP   1184896
#define WS_RESTH   1187456
#define WS_RESTM   1711744
#define WS_RESTL   2236032
#define WS_EMBH    2760320
#define WS_EMBM    2825856
#define WS_EMBL    2891392
#define WS_WSPL    2956928
// end 3012224 floats = 11.5 MB

typedef __attribute__((ext_vector_type(8))) short short8_t;
typedef __attribute__((ext_vector_type(4))) float f32x4;
typedef unsigned long long ull;
#define MFMA(a,b,c) __builtin_amdgcn_mfma_f32_16x16x32_bf16((a),(b),(c),0,0,0)

__device__ inline void gl_lds16(const void* g, void* l) {
  __builtin_amdgcn_global_load_lds((const __attribute__((address_space(1))) void*)g,
                                   (__attribute__((address_space(3))) void*)l, 16, 0, 0);
}
__device__ inline void gl_lds4(const void* g, void* l) {
  __builtin_amdgcn_global_load_lds((const __attribute__((address_space(1))) void*)g,
                                   (__attribute__((address_space(3))) void*)l, 4, 0, 0);
}

// split f32 -> 3 truncated bf16 levels (captures ~24 bits)
__device__ inline void split3(float a, ushort* h, ushort* m, ushort* l) {
  unsigned ua = __float_as_uint(a);
  ushort uh = (ushort)(ua >> 16);
  float fh = __uint_as_float((unsigned)uh << 16);
  float r1 = a - fh;
  ushort um = (ushort)(__float_as_uint(r1) >> 16);
  float fm = __uint_as_float((unsigned)um << 16);
  float r2 = r1 - fm;
  ushort ul = (ushort)(__float_as_uint(r2) >> 16);
  *h = uh; *m = um; *l = ul;
}

// DPP lane shifts within 16-lane rows; bound_ctrl=1 -> zero fill (SAME pad)
__device__ inline short8_t s8_from_laneM1(short8_t v) {
  union { short8_t s; unsigned u[4]; } a, r;
  a.s = v;
#pragma unroll
  for (int i = 0; i < 4; ++i)
    r.u[i] = __builtin_amdgcn_update_dpp(0u, a.u[i], 0x111, 0xF, 0xF, true);
  return r.s;
}
__device__ inline short8_t s8_from_laneP1(short8_t v) {
  union { short8_t s; unsigned u[4]; } a, r;
  a.s = v;
#pragma unroll
  for (int i = 0; i < 4; ++i)
    r.u[i] = __builtin_amdgcn_update_dpp(0u, a.u[i], 0x101, 0xF, 0xF, true);
  return r.s;
}

// --------------------------- prep kernels -----------------------------------

__global__ __launch_bounds__(256) void k_prep(const float* __restrict__ emb,
                                              float* __restrict__ esq,
                                              ushort* __restrict__ eh,
                                              ushort* __restrict__ em,
                                              ushort* __restrict__ el,
                                              float* __restrict__ tw,
                                              int* __restrict__ ti,
                                              ull* __restrict__ slotA) {
  int bx = blockIdx.x, t = threadIdx.x;
  if (bx < 16) {
    int v = bx * 256 + t;
    const float4* e4 = (const float4*)(emb + (size_t)v * 32);
    float s = 0.f;
#pragma unroll
    for (int half = 0; half < 4; ++half) {
      float4 x0 = e4[half * 2], x1 = e4[half * 2 + 1];
      s += x0.x * x0.x + x0.y * x0.y + x0.z * x0.z + x0.w * x0.w;
      s += x1.x * x1.x + x1.y * x1.y + x1.z * x1.z + x1.w * x1.w;
      float xs[8] = {x0.x, x0.y, x0.z, x0.w, x1.x, x1.y, x1.z, x1.w};
      ushort hs[8], ms[8], ls[8];
#pragma unroll
      for (int j = 0; j < 8; ++j) split3(xs[j], &hs[j], &ms[j], &ls[j]);
      uint4 ph, pm, pl;
      ph.x = (unsigned)hs[0] | ((unsigned)hs[1] << 16); ph.y = (unsigned)hs[2] | ((unsigned)hs[3] << 16);
      ph.z = (unsigned)hs[4] | ((unsigned)hs[5] << 16); ph.w = (unsigned)hs[6] | ((unsigned)hs[7] << 16);
      pm.x = (unsigned)ms[0] | ((unsigned)ms[1] << 16); pm.y = (unsigned)ms[2] | ((unsigned)ms[3] << 16);
      pm.z = (unsigned)ms[4] | ((unsigned)ms[5] << 16); pm.w = (unsigned)ms[6] | ((unsigned)ms[7] << 16);
      pl.x = (unsigned)ls[0] | ((unsigned)ls[1] << 16); pl.y = (unsigned)ls[2] | ((unsigned)ls[3] << 16);
      pl.z = (unsigned)ls[4] | ((unsigned)ls[5] << 16); pl.w = (unsigned)ls[6] | ((unsigned)ls[7] << 16);
      ((uint4*)(eh + (size_t)v * 32))[half] = ph;
      ((uint4*)(em + (size_t)v * 32))[half] = pm;
      ((uint4*)(el + (size_t)v * 32))[half] = pl;
    }
    esq[v] = -0.5f * s;
  } else {
    if (t < 128) slotA[t] = 0ULL;     // si=0 argmax slots
    if (t >= 144) return;
    const int pns[9] = {1, 2, 3, 4, 5, 6, 8, 10, 13};
    int si = t / 16, Y = t % 16;
    int pn = pns[si];
    double src = (Y + 0.5) * (double)pn / 16.0 - 0.5;
    double fl = floor(src);
    const double a = -0.75;
#pragma unroll
    for (int k = 0; k < 4; ++k) {
      double x = fabs(src - (fl + (k - 1)));
      double w;
      if (x <= 1.0)      w = (a + 2.0) * x * x * x - (a + 3.0) * x * x + 1.0;
      else if (x < 2.0)  w = a * x * x * x - 5.0 * a * x * x + 8.0 * a * x - 4.0 * a;
      else               w = 0.0;
      int id = (int)fl + (k - 1);
      id = id < 0 ? 0 : (id > pn - 1 ? pn - 1 : id);
      tw[si * 64 + Y * 4 + k] = (float)w;
      ti[si * 64 + Y * 4 + k] = id;
    }
  }
}

__global__ __launch_bounds__(256) void k_prep2(const float* __restrict__ f,
                                               const float* __restrict__ phiW,
                                               ushort* __restrict__ rh,
                                               ushort* __restrict__ rm,
                                               ushort* __restrict__ rl,
                                               ushort* __restrict__ wspl) {
  int bx = blockIdx.x, t = threadIdx.x;
  if (bx < 16) {
    // phi weight split: wspl[phi][lvl*9+q][o][ci]
    int i = bx * 256 + t;   // 4096 (phi,o,ci)
    int phi = i >> 10, o = (i >> 5) & 31, ci = i & 31;
    const float* src = phiW + (((size_t)phi * 32 + o) * 32 + ci) * 9;
    ushort* dst = wspl + (size_t)phi * 27648;
#pragma unroll
    for (int q = 0; q < 9; ++q) {
      ushort uh, um, ul;
      split3(src[q], &uh, &um, &ul);
      dst[(size_t)(0 * 9 + q) * 1024 + o * 32 + ci] = uh;
      dst[(size_t)(9 + q) * 1024 + o * 32 + ci] = um;
      dst[(size_t)(18 + q) * 1024 + o * 32 + ci] = ul;
    }
  } else {
    // si=0 NN input: area-pool f to 1x1 -> [n][c] 3-level bf16
    int tid = (bx - 16) * 256 + t;   // 4096
    int c = tid & 31, n = tid >> 5;
    const float* base = f + ((size_t)n * 32 + c) * 256;
    float s = 0.f;
    for (int yy = 0; yy < 16; ++yy)
      for (int xx = 0; xx < 16; ++xx) s += base[yy * 16 + xx];
    float a = s * ((1.0f / 16.0f) * (1.0f / 16.0f));
    ushort uh, um, ul;
    split3(a, &uh, &um, &ul);
    rh[(size_t)n * 32 + c] = uh;
    rm[(size_t)n * 32 + c] = um;
    rl[(size_t)n * 32 + c] = ul;
  }
}

// --------------------------- NN search (round-7, unchanged) -----------------
template<int R>
__global__ __launch_bounds__(256) void k_nn(const ushort* __restrict__ rest_h,
                                            const ushort* __restrict__ rest_m,
                                            const ushort* __restrict__ rest_l,
                                            const ushort* __restrict__ emb_h,
                                            const ushort* __restrict__ emb_m,
                                            const ushort* __restrict__ emb_l,
                                            const float* __restrict__ esq_g,
                                            ull* __restrict__ slot,
                                            int rows, int S, int cps) {
  __shared__ ushort lb[2][3][2048];
  __shared__ float les[2][64];
  const int t = threadIdx.x;
  const int w = t >> 6;
  const int col = t & 15;
  const int g = (t >> 4) & 3;
  const int sp = blockIdx.y;
  const int rowbase = blockIdx.x * (64 * R);

  auto stage = [&](int bf, int ch) {
    int cb = sp * cps + ch * 64;
    int code = cb + (t >> 2);
    int u = (t & 3) ^ ((code ^ (code >> 2)) & 3);
    size_t off = (size_t)code * 32 + (size_t)u * 8;
    gl_lds16(emb_h + off, &lb[bf][0][w * 512]);
    gl_lds16(emb_m + off, &lb[bf][1][w * 512]);
    gl_lds16(emb_l + off, &lb[bf][2][w * 512]);
    if ((t & 63) < 16) gl_lds4(esq_g + cb + w * 16 + (t & 15), &les[bf][w * 16]);
  };

  stage(0, 0);

  short8_t ah[R], am[R], al[R];
#pragma unroll
  for (int rt = 0; rt < R; ++rt) {
    int n = rowbase + (w * R + rt) * 16 + col;
    if (n >= rows) n = rows - 1;
    size_t o = (size_t)n * 32 + g * 8;
    ah[rt] = *(const short8_t*)(rest_h + o);
    am[rt] = *(const short8_t*)(rest_m + o);
    al[rt] = *(const short8_t*)(rest_l + o);
  }

  float best[R][4];
  int bidx[R][4];
#pragma unroll
  for (int rt = 0; rt < R; ++rt)
#pragma unroll
    for (int r = 0; r < 4; ++r) { best[rt][r] = -3.4e38f; bidx[rt][r] = 0x7fffffff; }

  const int NC = cps >> 6;
  int buf = 0;
  for (int ch = 0; ch < NC; ++ch) {
    if (ch + 1 < NC) {
      stage(buf ^ 1, ch + 1);
      asm volatile("s_waitcnt vmcnt(4)" ::: "memory");
    } else {
      asm volatile("s_waitcnt vmcnt(0)" ::: "memory");
    }
    __builtin_amdgcn_s_barrier();

    int cb0 = sp * cps + ch * 64;
#pragma unroll
    for (int s4 = 0; s4 < 4; ++s4) {
      int cl = s4 * 16 + col;
      int slotbase = (cl * 4 + (g ^ ((cl ^ (cl >> 2)) & 3))) * 8;
      short8_t bh  = *(const short8_t*)&lb[buf][0][slotbase];
      short8_t bm  = *(const short8_t*)&lb[buf][1][slotbase];
      short8_t bl2 = *(const short8_t*)&lb[buf][2][slotbase];
      float es = les[buf][cl];
      f32x4 c0 = {es, es, es, es};
      f32x4 acc[R];
      // per-acc order identical to rounds 2-7: hh,hm,mh,hl,mm,lh
#pragma unroll
      for (int rt = 0; rt < R; ++rt) acc[rt] = MFMA(ah[rt], bh, c0);
#pragma unroll
      for (int rt = 0; rt < R; ++rt) acc[rt] = MFMA(ah[rt], bm, acc[rt]);
#pragma unroll
      for (int rt = 0; rt < R; ++rt) acc[rt] = MFMA(am[rt], bh, acc[rt]);
#pragma unroll
      for (int rt = 0; rt < R; ++rt) acc[rt] = MFMA(ah[rt], bl2, acc[rt]);
#pragma unroll
      for (int rt = 0; rt < R; ++rt) acc[rt] = MFMA(am[rt], bm, acc[rt]);
#pragma unroll
      for (int rt = 0; rt < R; ++rt) acc[rt] = MFMA(al[rt], bh, acc[rt]);
      int code = cb0 + cl;
#pragma unroll
      for (int rt = 0; rt < R; ++rt)
#pragma unroll
        for (int r = 0; r < 4; ++r)
          if (acc[rt][r] > best[rt][r]) { best[rt][r] = acc[rt][r]; bidx[rt][r] = code; }
    }
    __syncthreads();
    buf ^= 1;
  }

  // 16-lane reduce then one packed atomicMax per row:
  // key = (monotone(acc) << 32) | ~idx  ==  max acc, tie -> min idx
#pragma unroll
  for (int rt = 0; rt < R; ++rt)
#pragma unroll
    for (int r = 0; r < 4; ++r) {
      float bd = best[rt][r];
      int bi = bidx[rt][r];
#pragma unroll
      for (int mm2 = 1; mm2 < 16; mm2 <<= 1) {
        float od = __shfl_xor(bd, mm2, 16);
        int oi = __shfl_xor(bi, mm2, 16);
        if (od > bd || (od == bd && oi < bi)) { bd = od; bi = oi; }
      }
      if ((t & 15) == 0) {
        int rown = rowbase + (w * R + rt) * 16 + g * 4 + r;
        if (rown < rows) {
          unsigned mu = __float_as_uint(bd);
          mu ^= (mu & 0x80000000u) ? 0xFFFFFFFFu : 0x80000000u;
          ull key = ((ull)mu << 32) | (unsigned)(~bi);
          atomicMax(&slot[rown], key);
        }
      }
    }
}

// --------------------------- fused per-scale kernel -------------------------
// grid (B,2), 1024 thr, 16 out-ch per block. Phases:
//  0: fr prefetch + weights->LDS + slots->codes (+idx out)      [barrier]
//  1a: coalesced float4 emb gather -> hsm (or h_bf for LAST)    [barrier]
//  1b: wave-owned x/y bicubic interp -> h_bf + h_my             [barrier]
//  2: MFMA conv (wave = image row) + f_rest RMW + pool staging  [barrier]
//  3: coalesced pool + next-slot zero + loss partial
template<bool LAST>
__global__ __launch_bounds__(1024) void k_scale(const ull* __restrict__ slot_in,
                                                ull* __restrict__ slot_next,
                                                const float* __restrict__ emb,
                                                const float* __restrict__ tw,
                                                const int* __restrict__ ti,
                                                const ushort* __restrict__ wspl,
                                                const float* __restrict__ bias,
                                                const float* __restrict__ f,
                                                const float* __restrict__ fr_in,
                                                float* __restrict__ fr_out,
                                                float* __restrict__ fhat_out,
                                                float* __restrict__ out_idx_f,
                                                float* __restrict__ lossp,
                                                ushort* __restrict__ rh,
                                                ushort* __restrict__ rm,
                                                ushort* __restrict__ rl,
                                                int pn, int si, int pn_next,
                                                int rows_next) {
  __shared__ ushort h_bf[3][256][40];      // 61440 B
  __shared__ float hsm[32 * 177];          // 22656 B (poolb later)
  __shared__ float xt[32][208];            // 26624 B
  __shared__ float h_my[16][260];          // 16640 B
  __shared__ ushort w_lds[27][16][36];     // 31104 B
  __shared__ int ci_s[256];
  __shared__ float redw[16];
  float* poolb = hsm;

  const int b = blockIdx.x;
  const int cog = blockIdx.y * 16;
  const int t = threadIdx.x;
  const int pn2 = pn * pn;
  const int w = t >> 6, l = t & 63;
  const int X = l & 15, kq = l >> 4;
  const int pix = w * 16 + X;

  // ---- phase 0: early fr prefetch (consumed in phase 2)
  float fr_old[4], f_old[4];
#pragma unroll
  for (int r = 0; r < 4; ++r) {
    size_t ga = ((size_t)b * 32 + cog + kq * 4 + r) * 256 + pix;
    fr_old[r] = fr_in[ga];
    f_old[r] = LAST ? f[ga] : 0.f;
  }
  for (int i = t; i < 1728; i += 1024) {
    int seg = i & 3;
    int o = (i >> 2) & 15;
    int lq = i >> 6;
    const ushort* src = wspl + ((size_t)lq * 32 + cog + o) * 32 + seg * 8;
    *(short8_t*)&w_lds[lq][o][seg * 8] = *(const short8_t*)src;
  }
  for (int rem = t; rem < pn2; rem += 1024) {
    ull sv = slot_in[b * pn2 + rem];
    int code = (int)(~(unsigned)sv);
    ci_s[rem] = code;
    out_idx_f[b * pn2 + rem] = (float)code;
  }
  __syncthreads();

  // ---- phase 1a: coalesced emb gather (float4 per 8 threads per code row)
  if (LAST) {
    const float4* emb4 = (const float4*)emb;
    for (int i = t; i < 2048; i += 1024) {
      int p2 = i >> 3, cq = i & 7;
      float4 e = emb4[(size_t)ci_s[p2] * 8 + cq];
      float vs[4] = {e.x, e.y, e.z, e.w};
#pragma unroll
      for (int j = 0; j < 4; ++j) {
        int c = cq * 4 + j;
        ushort uh, um, ul; split3(vs[j], &uh, &um, &ul);
        h_bf[0][p2][c] = uh; h_bf[1][p2][c] = um; h_bf[2][p2][c] = ul;
        int cl = c - cog;
        if ((unsigned)cl < 16u) h_my[cl][p2] = vs[j];
      }
    }
    __syncthreads();
  } else {
    const float4* emb4 = (const float4*)emb;
    for (int i = t; i < pn2 * 8; i += 1024) {
      int rem = i >> 3, cq = i & 7;
      float4 e = emb4[(size_t)ci_s[rem] * 8 + cq];
      hsm[(cq * 4 + 0) * 177 + rem] = e.x;
      hsm[(cq * 4 + 1) * 177 + rem] = e.y;
      hsm[(cq * 4 + 2) * 177 + rem] = e.z;
      hsm[(cq * 4 + 3) * 177 + rem] = e.w;
    }
    __syncthreads();

    // ---- phase 1b: wave w owns channels {2w, 2w+1}: x-interp then y-interp
#pragma unroll
    for (int cc = 0; cc < 2; ++cc) {
      int c = 2 * w + cc;
      for (int i = l; i < pn * 16; i += 64) {
        int Xi = i & 15, y = i >> 4;
        float a = 0.f;
#pragma unroll
        for (int u = 0; u < 4; ++u)
          a += tw[si * 64 + Xi * 4 + u] * hsm[c * 177 + y * pn + ti[si * 64 + Xi * 4 + u]];
        xt[c][y * 16 + Xi] = a;
      }
      asm volatile("s_waitcnt lgkmcnt(0)" ::: "memory");   // wave-local RAW fence
      for (int p2 = l; p2 < 256; p2 += 64) {
        int Xi = p2 & 15, Y = p2 >> 4;
        float a = 0.f;
#pragma unroll
        for (int u = 0; u < 4; ++u)
          a += tw[si * 64 + Y * 4 + u] * xt[c][ti[si * 64 + Y * 4 + u] * 16 + Xi];
        ushort uh, um, ul; split3(a, &uh, &um, &ul);
        h_bf[0][p2][c] = uh; h_bf[1][p2][c] = um; h_bf[2][p2][c] = ul;
        int cl = c - cog;
        if ((unsigned)cl < 16u) h_my[cl][p2] = a;
      }
    }
    __syncthreads();
  }

  // ---- phase 2: conv via MFMA (wave = image row w), then epilogue
  f32x4 accA, accB;
#pragma unroll
  for (int r = 0; r < 4; ++r) {
    accA[r] = bias[cog + kq * 4 + r];
    accB[r] = 0.f;
  }

  for (int dy = 0; dy < 3; ++dy) {
    int Yp = w + dy - 1;
    bool ok = (Yp >= 0 && Yp < 16);
    short8_t bc[3];
    if (ok) {
#pragma unroll
      for (int lv = 0; lv < 3; ++lv)
        bc[lv] = *(const short8_t*)&h_bf[lv][Yp * 16 + X][kq * 8];
    }
#pragma unroll
    for (int dx = 0; dx < 3; ++dx) {
      int q = dy * 3 + dx;
      short8_t aH = *(const short8_t*)&w_lds[0 * 9 + q][l & 15][kq * 8];
      short8_t aM = *(const short8_t*)&w_lds[9 + q][l & 15][kq * 8];
      short8_t aL = *(const short8_t*)&w_lds[18 + q][l & 15][kq * 8];
      if (!ok) continue;
      short8_t bH = bc[0], bM = bc[1], bL = bc[2];
      if (dx == 0) { bH = s8_from_laneM1(bH); bM = s8_from_laneM1(bM); bL = s8_from_laneM1(bL); }
      else if (dx == 2) { bH = s8_from_laneP1(bH); bM = s8_from_laneP1(bM); bL = s8_from_laneP1(bL); }
      accA = MFMA(aH, bH, accA);
      accB = MFMA(aH, bM, accB);
      accA = MFMA(aM, bH, accA);
      accB = MFMA(aH, bL, accB);
      accA = MFMA(aM, bM, accA);
      accB = MFMA(aL, bH, accB);
    }
  }

  float lsum = 0.f;
#pragma unroll
  for (int r = 0; r < 4; ++r) {
    int ol = kq * 4 + r;
    float convv = accA[r] + accB[r];
    float outv = 0.5f * h_my[ol][pix] + 0.5f * convv;
    float nf = fr_old[r] - outv;
    size_t ga = ((size_t)b * 32 + cog + ol) * 256 + pix;
    if (LAST) {
      fhat_out[ga] = f_old[r] - nf;
    } else {
      fr_out[ga] = nf;
      poolb[ol * 256 + pix] = nf;
    }
    lsum += nf * nf;
  }

  // ---- phase 3: coalesced pool + next-slot zero + loss
  if (!LAST) {
    __syncthreads();
    int pn2n = pn_next * pn_next;
    // o-minor mapping: 16 consecutive lanes write 16 consecutive ushorts
    for (int i = t; i < 16 * pn2n; i += 1024) {
      int o = i & 15, rem = i >> 4;
      int y = rem / pn_next, x = rem - y * pn_next;
      int sy = (y * 16) / pn_next, ey = ((y + 1) * 16 + pn_next - 1) / pn_next;
      int sx = (x * 16) / pn_next, ex = ((x + 1) * 16 + pn_next - 1) / pn_next;
      float s = 0.f;
      for (int yy = sy; yy < ey; ++yy)
        for (int xx = sx; xx < ex; ++xx) s += poolb[o * 256 + yy * 16 + xx];
      float a = s * ((1.0f / (float)(ey - sy)) * (1.0f / (float)(ex - sx)));
      ushort uh, um, ul;
      split3(a, &uh, &um, &ul);
      size_t n = (size_t)b * pn2n + rem;
      rh[n * 32 + cog + o] = uh;
      rm[n * 32 + cog + o] = um;
      rl[n * 32 + cog + o] = ul;
    }
    int blk = b * 2 + blockIdx.y;                 // 0..255
    int stride = (rows_next + 255) >> 8;
    int base = blk * stride;
    for (int i = t; i < stride; i += 1024) {
      int s = base + i;
      if (s < rows_next) slot_next[s] = 0ULL;
    }
  }

#pragma unroll
  for (int off = 32; off > 0; off >>= 1) lsum += __shfl_down(lsum, off);
  if (l == 0) redw[w] = lsum;
  __syncthreads();
  if (t == 0) {
    float s2 = 0.f;
#pragma unroll
    for (int i = 0; i < 16; ++i) s2 += redw[i];
    lossp[si * 256 + blockIdx.y * 128 + b] = s2;
  }
}

__global__ __launch_bounds__(256) void k_lossfin(const float* __restrict__ part,
                                                 float* __restrict__ out) {
  int t = threadIdx.x;
  float s = 0.f;
  for (int i = t; i < SN_ * 256; i += 256) s += part[i];
  __shared__ float red[256];
  red[t] = s;
  __syncthreads();
  for (int o = 128; o > 0; o >>= 1) {
    if (t < o) red[t] += red[t + o];
    __syncthreads();
  }
  if (t == 0) out[NPIX_] = red[0] * (1.25f / (10.0f * (float)NPIX_));
}

// --------------------------- host side -------------------------------------

static void compute_phi_k(int* ks) {
  const int K = 4;
  double start = 1.0 / (3.0 * K);
  double stop = 1.0 - 1.0 / (3.0 * K);
  double step = (stop - start) / (K - 1);
  double ticks[4];
  for (int i = 0; i < K; ++i) ticks[i] = (double)i * step + start;
  ticks[K - 1] = stop;
  for (int si = 0; si < SN_; ++si) {
    double x = (double)si / (SN_ - 1);
    int best = 0;
    double bd = fabs(ticks[0] - x);
    for (int i = 1; i < K; ++i) {
      double d = fabs(ticks[i] - x);
      if (d < bd) { bd = d; best = i; }
    }
    ks[si] = best;
  }
}

extern "C" void kernel_launch(void* const* d_in, const int* in_sizes, int n_in,
                              void* d_out, int out_size, void* d_ws, size_t ws_size,
                              hipStream_t stream) {
  (void)in_sizes; (void)n_in; (void)out_size; (void)ws_size;
  const float* f    = (const float*)d_in[0];
  const float* emb  = (const float*)d_in[1];
  const float* phiW = (const float*)d_in[2];
  const float* phiB = (const float*)d_in[3];
  float* out = (float*)d_out;
  float* ws = (float*)d_ws;

  float* f_rest = ws + WS_FREST;
  ull*   slotA  = (ull*)(ws + WS_SLOTA);
  ull*   slotB  = (ull*)(ws + WS_SLOTB);
  float* esq    = ws + WS_ESQ;
  float* tw     = ws + WS_TW;
  int*   ti     = (int*)(ws + WS_TI);
  float* lossp  = ws + WS_LOSSP;
  ushort* rest_h = (ushort*)(ws + WS_RESTH);
  ushort* rest_m = (ushort*)(ws + WS_RESTM);
  ushort* rest_l = (ushort*)(ws + WS_RESTL);
  ushort* emb_h  = (ushort*)(ws + WS_EMBH);
  ushort* emb_m  = (ushort*)(ws + WS_EMBM);
  ushort* emb_l  = (ushort*)(ws + WS_EMBL);
  ushort* wspl   = (ushort*)(ws + WS_WSPL);

  static const int pns[SN_] = {1, 2, 3, 4, 5, 6, 8, 10, 13, 16};
  static const int Rs[SN_]  = {1, 1, 1, 2, 2, 2, 4, 4, 4, 4};
  static const int Ss[SN_]  = {64, 64, 32, 32, 16, 16, 16, 16, 8, 4};
  int ks[SN_];
  compute_phi_k(ks);

  k_prep<<<17, 256, 0, stream>>>(emb, esq, emb_h, emb_m, emb_l, tw, ti, slotA);
  k_prep2<<<32, 256, 0, stream>>>(f, phiW, rest_h, rest_m, rest_l, wspl);

  int idx_off = 0;
  for (int si = 0; si < SN_; ++si) {
    int pn = pns[si];
    int pn2 = pn * pn;
    int rows = B_ * pn2;
    int R = Rs[si], S = Ss[si];
    int cps = V_ / S;
    int rowblocks = (rows + 64 * R - 1) / (64 * R);
    ull* slot_cur  = (si & 1) ? slotB : slotA;
    ull* slot_nxt  = (si & 1) ? slotA : slotB;

    dim3 grid(rowblocks, S);
    if (R == 1)
      k_nn<1><<<grid, 256, 0, stream>>>(rest_h, rest_m, rest_l, emb_h, emb_m, emb_l,
                                        esq, slot_cur, rows, S, cps);
    else if (R == 2)
      k_nn<2><<<grid, 256, 0, stream>>>(rest_h, rest_m, rest_l, emb_h, emb_m, emb_l,
                                        esq, slot_cur, rows, S, cps);
    else
      k_nn<4><<<grid, 256, 0, stream>>>(rest_h, rest_m, rest_l, emb_h, emb_m, emb_l,
                                        esq, slot_cur, rows, S, cps);

    bool last = (si == SN_ - 1);
    int pn_next = last ? 0 : pns[si + 1];
    int rows_next = last ? 0 : B_ * pn_next * pn_next;
    const ushort* wsp = wspl + (size_t)ks[si] * 27648;
    const float* bi = phiB + (size_t)ks[si] * 32;
    if (last)
      k_scale<true><<<dim3(B_, 2), 1024, 0, stream>>>(
          slot_cur, slot_nxt, emb, tw, ti, wsp, bi, f,
          f_rest, f_rest, out,
          out + NPIX_ + 1 + idx_off, lossp,
          rest_h, rest_m, rest_l, pn, si, pn_next, rows_next);
    else
      k_scale<false><<<dim3(B_, 2), 1024, 0, stream>>>(
          slot_cur, slot_nxt, emb, tw, ti, wsp, bi, f,
          (si == 0) ? f : f_rest, f_rest, nullptr,
          out + NPIX_ + 1 + idx_off, lossp,
          rest_h, rest_m, rest_l, pn, si, pn_next, rows_next);
    idx_off += rows;
  }

  k_lossfin<<<1, 256, 0, stream>>>(lossp, out);
}